// Round 9
// baseline (2541.599 us; speedup 1.0000x reference)
//
#include <hip/hip_runtime.h>

typedef float f32x4 __attribute__((ext_vector_type(4)));
typedef int   i32x4 __attribute__((ext_vector_type(4)));
typedef short s16x8 __attribute__((ext_vector_type(8)));

#define VOCAB 256
#define EMB   128
#define HID   512
#define OUT_D 256
#define BATCH 64
#define SEQ   1024

__device__ __forceinline__ unsigned short f2bf(float f) {
  unsigned u = __builtin_bit_cast(unsigned, f);
  u += 0x7fffu + ((u >> 16) & 1u);
  return (unsigned short)(u >> 16);
}

// ---------------------------------------------------------------------------
// Prep 1: E2[v][c] = sum_e emb[v][e]*We[e][c] + bh[c]   (f32, 256x512)
// ---------------------------------------------------------------------------
__global__ void k_e2(const float* __restrict__ emb, const float* __restrict__ We,
                     const float* __restrict__ bh, float* __restrict__ E2)
{
  __shared__ float el[EMB];
  const int v = blockIdx.x, c = threadIdx.x;   // 512 threads
  if (c < EMB) el[c] = emb[v * EMB + c];
  __syncthreads();
  float s = bh[c];
  #pragma unroll
  for (int e = 0; e < EMB; ++e) s += el[e] * We[e * HID + c];
  E2[v * HID + c] = s;
}

// ---------------------------------------------------------------------------
// Prep 2: W_h -> int8 (x2048) packed as MFMA B-fragments for 16x16x64 i8.
// frag = ct*8+kt (ct = coltile 0..31): lane holds B[k'][ct*16+(lane&15)],
// k' = kt*64 + (lane>>4)*16 + j
// ---------------------------------------------------------------------------
__global__ void k_whfrag(const float* __restrict__ Wh, i32x4* __restrict__ WhF)
{
  const int g = blockIdx.x * 256 + threadIdx.x;   // 0..16383
  const int lane = g & 63, frag = g >> 6;         // frag 0..255
  const int kt = frag & 7, ct = frag >> 3;        // ct 0..31
  const int col = (ct << 4) + (lane & 15);
  const int kb  = (kt << 6) + ((lane >> 4) << 4);
  int wd[4];
  #pragma unroll
  for (int q = 0; q < 4; ++q) {
    int b[4];
    #pragma unroll
    for (int j = 0; j < 4; ++j) {
      float s = Wh[(kb + q * 4 + j) * HID + col] * 2048.f;
      s = fminf(fmaxf(s, -127.f), 127.f);
      b[j] = __float2int_rn(s) & 255;
    }
    wd[q] = b[0] | (b[1] << 8) | (b[2] << 16) | (b[3] << 24);
  }
  i32x4 v = {wd[0], wd[1], wd[2], wd[3]};
  WhF[g] = v;
}

// ---------------------------------------------------------------------------
// Prep 3: W_o -> bf16 transposed AND pre-scaled by 1/127 (hist is int8 x127):
// WoT[col][k] = bf16(Wo[k][col] / 127)
// ---------------------------------------------------------------------------
__global__ void k_wot(const float* __restrict__ Wo, unsigned short* __restrict__ WoT)
{
  const int k = blockIdx.x;      // 512
  const int c = threadIdx.x;     // 256
  WoT[c * HID + k] = f2bf(Wo[k * OUT_D + c] * (1.0f / 127.0f));
}

// ---------------------------------------------------------------------------
// Scan: 128 WGs x 512 thr. Block b -> (row = b&63, half H = b>>6); the two
// halves of one row's recurrence run on partner WGs. Each WG owns 256 cols:
// 16 ct x 8 kt = 128 MFMAs = 32/SIMD (~653 cy) -- HALF the single-WG cost.
// Per step the 256-byte h-half is exchanged via device-scope relaxed atomics
// with SELF-TAGGED payload (dword = 2 h-bytes | step-tag<<16): one round trip,
// no flag ordering. Phase A consumes the locally-produced kt half while the
// remote half is in flight; consumer wave (wv==1) lands it; barrier; phase B.
// Publish is distributed per-wave right after tanh (wave-local lgkmcnt only).
// 2-parity buffers; tags zeroed per launch (graph replays can't stale-match).
// HIST INDEXING (round-8 bug): hbuf[PH] at step t = outputs[t-1] -> its flush
// goes to slot t-1 (guard t>0), exactly as rounds 4-6 did. Final flush:
// STEP(1023,PH=1) writes outputs[1023] into hbuf[0] -> slot 1023.
// ---------------------------------------------------------------------------
__global__ __launch_bounds__(512, 2) void k_scan(
    const int* __restrict__ x, const float* __restrict__ h0,
    const float* __restrict__ E2, const i32x4* __restrict__ WhF,
    unsigned int* __restrict__ xb,
    char* __restrict__ hist, float* __restrict__ fh)
{
  __shared__ __align__(16) char hbuf[2][HID];   // 2 x 512B int8 full h
  const int tid  = threadIdx.x;
  const int wv   = tid >> 6, lane = tid & 63;
  const int lrow = lane & 15, lhi = lane >> 4;
  const int b    = blockIdx.x;
  const int row  = b & 63, H = b >> 6;
  const int colL = (wv << 5) + ((lhi & 1) << 4) + lrow;   // 0..255 in half
  const int col  = (H << 8) + colL;                       // global hidden col

  // W_h B-fragments: ct = H*16 + wv*2 + nt, kt 0..7
  i32x4 bfr[2][8];
  #pragma unroll
  for (int nt = 0; nt < 2; ++nt)
    #pragma unroll
    for (int kt = 0; kt < 8; ++kt)
      bfr[nt][kt] = WhF[(((H << 4) + (wv << 1) + nt) * 8 + kt) * 64 + lane];

  // A-read bases: local kt set = {H*4..H*4+3} -> bytes [H*256, H*256+256)
  const int hbL = (H << 8) + (lhi << 4);          // + k4*64
  const int hbR = ((1 - H) << 8) + (lhi << 4);    // + k4*64
  // publish (lane<16): this wave's 32 bytes as 16 tagged dwords
  const int pubLds = (H << 8) + (wv << 5) + (lane << 1);
  // exchange buffers: xb[row][H][par][128] u32
  unsigned int* const xb_my = xb + (((row << 1) + H) << 8);        // + par*128
  unsigned int* const xb_pt = xb + (((row << 1) + (1 - H)) << 8);
  // consumer LDS dest (2 u16 per lane)
  const int conLds = ((1 - H) << 8) + (lane << 1);
  // hist (wave3, lane<16): this WG's 256-byte half of the row slot
  const int histLds = (H << 8) + (lane << 4);
  char* const histG = hist + ((size_t)row << 20) + (H << 8) + (lane << 4);

  // h0 -> int8 into hbuf[0] (full 512, both halves known at t=0)
  {
    float s = fminf(fmaxf(h0[(row << 9) + tid] * 127.f, -127.f), 127.f);
    hbuf[0][tid] = (char)__float2int_rn(s);
  }

  // prologue: hx(0) and id(1)
  const int id0 = x[(row << 10) + 0];
  int idA = x[(row << 10) + 1], idB;
  float hxA = E2[(id0 << 9) + col], hxB;
  __syncthreads();

  const float inv = 1.f / (127.f * 2048.f);
  const float TC  = 2.8853900817779268f;   // 2*log2(e)

#define STEP(T, PH, HXU, HXP, IDU, IDL)                                       \
  {                                                                           \
    const int t_ = (T);                                                       \
    /* read own half of hbuf[PH] = outputs[t-1] (stable all step) */          \
    i32x4 fvh;                                                                \
    if (wv == 3 && lane < 16) fvh = *(const i32x4*)(&hbuf[PH][histLds]);      \
    /* prefetch E2 value for t+1 and token id for t+2 */                      \
    HXP = E2[((IDU) << 9) + col];                                             \
    IDL = x[(row << 10) + ((t_ + 2 > SEQ - 1) ? SEQ - 1 : t_ + 2)];           \
    /* phase A: local kt (bytes this WG produced last step) */                \
    i32x4 acc[2] = {};                                                        \
    _Pragma("unroll") for (int k4 = 0; k4 < 4; ++k4) {                        \
      i32x4 a = *(const i32x4*)(&hbuf[PH][hbL + (k4 << 6)]);                  \
      const int kt = (H << 2) + k4;                                           \
      acc[0] = __builtin_amdgcn_mfma_i32_16x16x64_i8(a, bfr[0][kt], acc[0], 0, 0, 0); \
      acc[1] = __builtin_amdgcn_mfma_i32_16x16x64_i8(a, bfr[1][kt], acc[1], 0, 0, 0); \
    }                                                                         \
    /* consumer wave: land partner's half of h_t, then barrier #1 */          \
    if (t_ > 0) {                                                             \
      if (wv == 1) {                                                          \
        const unsigned int* src = xb_pt + ((t_ & 1) << 7);                    \
        unsigned int d0, d1;                                                  \
        const unsigned tag = (unsigned)t_;                                    \
        for (;;) {                                                            \
          d0 = __hip_atomic_load(src + lane,      __ATOMIC_RELAXED,           \
                                 __HIP_MEMORY_SCOPE_AGENT);                   \
          d1 = __hip_atomic_load(src + 64 + lane, __ATOMIC_RELAXED,           \
                                 __HIP_MEMORY_SCOPE_AGENT);                   \
          if (__all(((d0 >> 16) == tag) & ((d1 >> 16) == tag))) break;        \
        }                                                                     \
        *(unsigned short*)(&hbuf[PH][conLds])       = (unsigned short)d0;     \
        *(unsigned short*)(&hbuf[PH][conLds + 128]) = (unsigned short)d1;     \
      }                                                                       \
      asm volatile("s_waitcnt lgkmcnt(0)" ::: "memory");                      \
      __builtin_amdgcn_sched_barrier(0);                                      \
      __builtin_amdgcn_s_barrier();                                           \
      __builtin_amdgcn_sched_barrier(0);                                      \
    }                                                                         \
    /* phase B: remote kt */                                                  \
    _Pragma("unroll") for (int k4 = 0; k4 < 4; ++k4) {                        \
      i32x4 a = *(const i32x4*)(&hbuf[PH][hbR + (k4 << 6)]);                  \
      const int kt = ((1 - H) << 2) + k4;                                     \
      acc[0] = __builtin_amdgcn_mfma_i32_16x16x64_i8(a, bfr[0][kt], acc[0], 0, 0, 0); \
      acc[1] = __builtin_amdgcn_mfma_i32_16x16x64_i8(a, bfr[1][kt], acc[1], 0, 0, 0); \
    }                                                                         \
    /* hist store: outputs[t-1] -> slot t-1 (rounds 4-6 indexing) */          \
    if (t_ > 0 && wv == 3 && lane < 16)                                       \
      __builtin_nontemporal_store(fvh,                                        \
          (i32x4*)(histG + ((unsigned)(t_ - 1) << 10)));                      \
    /* epilogue: select copy, tanh, write own byte */                         \
    int av = (lhi & 1) ? acc[1][0] : acc[0][0];                               \
    float z = fmaf((float)av, inv, HXU);                                      \
    float e = __builtin_amdgcn_exp2f(z * TC);                                 \
    float h = fmaf(-2.f, __builtin_amdgcn_rcpf(1.f + e), 1.f);                \
    hbuf[1 - (PH)][col] = (char)__float2int_rn(h * 127.f);                    \
    if (t_ == SEQ - 1) fh[(row << 9) + col] = h;                              \
    /* distributed publish of the new half-slice (wave-local bytes only) */   \
    asm volatile("s_waitcnt lgkmcnt(0)" ::: "memory");                        \
    if (lane < 16) {                                                          \
      unsigned v16 = *(const unsigned short*)(&hbuf[1 - (PH)][pubLds]);       \
      unsigned dw = v16 | ((unsigned)(t_ + 1) << 16);                         \
      __hip_atomic_store(xb_my + (((t_ + 1) & 1) << 7) + (wv << 4) + lane,    \
                         dw, __ATOMIC_RELAXED, __HIP_MEMORY_SCOPE_AGENT);     \
    }                                                                         \
    asm volatile("s_waitcnt lgkmcnt(0)" ::: "memory");                        \
    __builtin_amdgcn_sched_barrier(0);                                        \
    __builtin_amdgcn_s_barrier();                                             \
    __builtin_amdgcn_sched_barrier(0);                                        \
  }

  for (int T2 = 0; T2 < SEQ / 2; ++T2) {
    STEP(2 * T2,     0, hxA, hxB, idA, idB)
    STEP(2 * T2 + 1, 1, hxB, hxA, idB, idA)
  }
#undef STEP

  // final hist flush: outputs[1023] was written by STEP(1023, PH=1) into
  // hbuf[1-PH] = hbuf[0] -> slot 1023
  if (wv == 3 && lane < 16) {
    i32x4 fvh = *(const i32x4*)(&hbuf[0][histLds]);
    __builtin_nontemporal_store(fvh, (i32x4*)(histG + ((unsigned)(SEQ - 1) << 10)));
  }
}

// ---------------------------------------------------------------------------
// Logits: A = int8 hist (512B prefix of each 1024B row slot) dequantized to
// bf16 during LDS staging (exact: |q|<=127 ints are exact bf16; 1/127 folded
// into WoT). GEMM in-place over d_out as before.
// ---------------------------------------------------------------------------
__global__ __launch_bounds__(256) void k_logits(const char* __restrict__ hist,
                                                const unsigned short* __restrict__ WoT,
                                                const float* __restrict__ bo, float* out)
{
  __shared__ __align__(16) char As[64 * 1024];
  const int tid = threadIdx.x;
  const int m0 = blockIdx.x * 64;

  // stage + dequant: 64 rows x 512 int8 -> bf16 tile with 16B-granule swizzle
  for (int i = tid; i < 1024; i += 256) {
    const int row = i >> 4, seg = i & 15;                 // 32 int8 cols/seg
    const char* src = hist + (size_t)(m0 + row) * 1024 + seg * 32;
    i32x4 w0 = *(const i32x4*)(src);
    i32x4 w1 = *(const i32x4*)(src + 16);
    unsigned od[16];
    #pragma unroll
    for (int d = 0; d < 8; ++d) {
      const unsigned dw = (unsigned)(d < 4 ? w0[d] : w1[d - 4]);
      const int q0 = (int)(signed char)(dw & 0xffu);
      const int q1 = (int)(signed char)((dw >> 8) & 0xffu);
      const int q2 = (int)(signed char)((dw >> 16) & 0xffu);
      const int q3 = (int)(signed char)(dw >> 24);
      const unsigned u0 = __builtin_bit_cast(unsigned, (float)q0);
      const unsigned u1 = __builtin_bit_cast(unsigned, (float)q1);
      const unsigned u2 = __builtin_bit_cast(unsigned, (float)q2);
      const unsigned u3 = __builtin_bit_cast(unsigned, (float)q3);
      od[2 * d]     = (u0 >> 16) | (u1 & 0xffff0000u);
      od[2 * d + 1] = (u2 >> 16) | (u3 & 0xffff0000u);
    }
    #pragma unroll
    for (int q = 0; q < 4; ++q) {
      i32x4 v = {(int)od[4 * q], (int)od[4 * q + 1],
                 (int)od[4 * q + 2], (int)od[4 * q + 3]};
      const int off = seg * 64 + q * 16;
      *(i32x4*)(&As[row * 1024 + (off ^ ((row & 7) << 4))]) = v;
    }
  }
  __syncthreads();

  const int wv = tid >> 6, lane = tid & 63, lrow = lane & 15, lhi = lane >> 4;
  const int cb = wv << 6;
  f32x4 acc[4][4] = {};
  #pragma unroll
  for (int kt = 0; kt < 16; ++kt) {
    s16x8 a[4], b[4];
    #pragma unroll
    for (int mt = 0; mt < 4; ++mt) {
      const int row = mt * 16 + lrow;
      a[mt] = *(const s16x8*)(&As[row * 1024 + ((kt * 64 + lhi * 16) ^ ((row & 7) << 4))]);
    }
    #pragma unroll
    for (int nt = 0; nt < 4; ++nt) {
      const int col = cb + nt * 16 + lrow;
      b[nt] = *(const s16x8*)((const char*)WoT + col * 1024 + kt * 64 + lhi * 16);
    }
    #pragma unroll
    for (int mt = 0; mt < 4; ++mt)
      #pragma unroll
      for (int nt = 0; nt < 4; ++nt)
        acc[mt][nt] = __builtin_amdgcn_mfma_f32_16x16x32_bf16(a[mt], b[nt], acc[mt][nt], 0, 0, 0);
  }
  #pragma unroll
  for (int nt = 0; nt < 4; ++nt) {
    const float bb = bo[cb + nt * 16 + lrow];
    #pragma unroll
    for (int mt = 0; mt < 4; ++mt)
      #pragma unroll
      for (int r = 0; r < 4; ++r)
        out[(size_t)(m0 + mt * 16 + lhi * 4 + r) * OUT_D + cb + nt * 16 + lrow] =
            acc[mt][nt][r] + bb;
  }
}

// ---------------------------------------------------------------------------
extern "C" void kernel_launch(void* const* d_in, const int* in_sizes, int n_in,
                              void* d_out, int out_size, void* d_ws, size_t ws_size,
                              hipStream_t stream)
{
  const int*   x   = (const int*)  d_in[0];
  const float* h0  = (const float*)d_in[1];
  const float* emb = (const float*)d_in[2];
  const float* We  = (const float*)d_in[3];
  const float* Wh  = (const float*)d_in[4];
  const float* bh  = (const float*)d_in[5];
  const float* Wo  = (const float*)d_in[6];
  const float* bo  = (const float*)d_in[7];
  float* out = (float*)d_out;
  char*  ws  = (char*)d_ws;

  float*          E2  = (float*)ws;                              // 512 KB
  i32x4*          WhF = (i32x4*)(ws + (512 << 10));              // 256 KB
  unsigned short* WoT = (unsigned short*)(ws + (768 << 10));     // 256 KB
  unsigned int*   xb  = (unsigned int*)(ws + (1024 << 10));      // 128 KB

  // tags must be invalid (=0) at every launch so graph replays can't
  // stale-match a previous run's exchange payloads
  hipMemsetAsync(xb, 0, 128 << 10, stream);

  k_e2    <<<VOCAB, HID,   0, stream>>>(emb, We, bh, E2);
  k_whfrag<<<64,    256,   0, stream>>>(Wh, WhF);
  k_wot   <<<HID,   OUT_D, 0, stream>>>(Wo, WoT);

  // int8 h history lives in the 512B prefix of each logits row of d_out;
  // k_logits then overwrites each row in-place after staging it to LDS.
  k_scan  <<<2 * BATCH, 512, 0, stream>>>(x, h0, E2, WhF, xb,
                                          (char*)d_out,
                                          out + (size_t)BATCH * SEQ * OUT_D);
  k_logits<<<(BATCH * SEQ) / 64, 256, 0, stream>>>(
      (const char*)d_out, WoT, bo, out);
}

// Round 10
// 729.803 us; speedup vs baseline: 3.4826x; 3.4826x over previous
//
#include <hip/hip_runtime.h>

typedef float f32x4 __attribute__((ext_vector_type(4)));
typedef int   i32x4 __attribute__((ext_vector_type(4)));
typedef short s16x8 __attribute__((ext_vector_type(8)));

#define VOCAB 256
#define EMB   128
#define HID   512
#define OUT_D 256
#define BATCH 64
#define SEQ   1024

__device__ __forceinline__ unsigned short f2bf(float f) {
  unsigned u = __builtin_bit_cast(unsigned, f);
  u += 0x7fffu + ((u >> 16) & 1u);
  return (unsigned short)(u >> 16);
}

// ---------------------------------------------------------------------------
// Prep 1: E2[v][c] = sum_e emb[v][e]*We[e][c] + bh[c]   (f32, 256x512)
// ---------------------------------------------------------------------------
__global__ void k_e2(const float* __restrict__ emb, const float* __restrict__ We,
                     const float* __restrict__ bh, float* __restrict__ E2)
{
  __shared__ float el[EMB];
  const int v = blockIdx.x, c = threadIdx.x;   // 512 threads
  if (c < EMB) el[c] = emb[v * EMB + c];
  __syncthreads();
  float s = bh[c];
  #pragma unroll
  for (int e = 0; e < EMB; ++e) s += el[e] * We[e * HID + c];
  E2[v * HID + c] = s;
}

// ---------------------------------------------------------------------------
// Prep 2: W_h -> int8 (x2048) packed as MFMA B-fragments for 16x16x64 i8.
// frag = ct*8+kt (ct = coltile 0..31): lane holds B[k'][ct*16+(lane&15)],
// k' = kt*64 + (lane>>4)*16 + j
// ---------------------------------------------------------------------------
__global__ void k_whfrag(const float* __restrict__ Wh, i32x4* __restrict__ WhF)
{
  const int g = blockIdx.x * 256 + threadIdx.x;   // 0..16383
  const int lane = g & 63, frag = g >> 6;         // frag 0..255
  const int kt = frag & 7, ct = frag >> 3;        // ct 0..31
  const int col = (ct << 4) + (lane & 15);
  const int kb  = (kt << 6) + ((lane >> 4) << 4);
  int wd[4];
  #pragma unroll
  for (int q = 0; q < 4; ++q) {
    int b[4];
    #pragma unroll
    for (int j = 0; j < 4; ++j) {
      float s = Wh[(kb + q * 4 + j) * HID + col] * 2048.f;
      s = fminf(fmaxf(s, -127.f), 127.f);
      b[j] = __float2int_rn(s) & 255;
    }
    wd[q] = b[0] | (b[1] << 8) | (b[2] << 16) | (b[3] << 24);
  }
  i32x4 v = {wd[0], wd[1], wd[2], wd[3]};
  WhF[g] = v;
}

// ---------------------------------------------------------------------------
// Prep 3: W_o -> bf16 transposed AND pre-scaled by 1/127 (hist is int8 x127):
// WoT[col][k] = bf16(Wo[k][col] / 127)
// ---------------------------------------------------------------------------
__global__ void k_wot(const float* __restrict__ Wo, unsigned short* __restrict__ WoT)
{
  const int k = blockIdx.x;      // 512
  const int c = threadIdx.x;     // 256
  WoT[c * HID + k] = f2bf(Wo[k * OUT_D + c] * (1.0f / 127.0f));
}

// ---------------------------------------------------------------------------
// Scan: 64 WGs x 1024 thr (16 waves, 4/SIMD); ONE batch row per WG.
// A-operand replicates the single h row across all 16 MFMA rows; every lane
// holds a valid copy of each col, so lane picks its col with ONE cndmask.
// Each wave covers 32 cols (2 nt x 8 kt = 16 MFMAs); per-SIMD MFMA issue is
// the 64-MFMA floor (1306 cy), and the tail is 4-way wave-overlapped.
// Cross-CU variants measured and rejected: sdot K-offload (r6: net-zero),
// 2-WG split w/ tagged atomic exchange (r9: +4000 cy/step coherence latency).
// ---------------------------------------------------------------------------
__global__ __launch_bounds__(1024, 4) void k_scan(
    const int* __restrict__ x, const float* __restrict__ h0,
    const float* __restrict__ E2, const i32x4* __restrict__ WhF,
    char* __restrict__ hist, float* __restrict__ fh)
{
  __shared__ __align__(16) char hbuf[2][HID];   // 2 x 512B int8 h
  const int tid  = threadIdx.x;
  const int wv   = tid >> 6, lane = tid & 63;
  const int lrow = lane & 15, lhi = lane >> 4;
  const int row  = blockIdx.x;                       // batch row (0..63)
  const int col  = (wv << 5) + ((lhi & 1) << 4) + lrow;  // this lane's col

  // W_h B-fragments -> registers (2 nt x 8 kt per wave; ct = wv*2+nt)
  i32x4 bfr[2][8];
  #pragma unroll
  for (int nt = 0; nt < 2; ++nt)
    #pragma unroll
    for (int kt = 0; kt < 8; ++kt)
      bfr[nt][kt] = WhF[((((wv << 1) + nt) << 3) + kt) * 64 + lane];

  // h0 -> int8 into hbuf[0] (one byte per thread, linear layout)
  if (tid < HID) {
    float s = fminf(fmaxf(h0[(row << 9) + tid] * 127.f, -127.f), 127.f);
    hbuf[0][tid] = (char)__float2int_rn(s);
  }

  // prologue: hx(0) and id(1)
  const int id0 = x[(row << 10) + 0];
  int idA = x[(row << 10) + 1], idB;
  float hxA = E2[(id0 << 9) + col], hxB;
  __syncthreads();

  const float inv = 1.f / (127.f * 2048.f);
  const float TC  = 2.8853900817779268f;   // 2*log2(e)

#define STEP(T, PH, HXU, HXP, IDU, IDL)                                       \
  {                                                                           \
    const int t_ = (T);                                                       \
    /* history flush read: hbuf[PH] = outputs[t-1], stable this step */       \
    i32x4 fv;                                                                 \
    if (tid < 32) fv = *(const i32x4*)(&hbuf[PH][tid << 4]);                  \
    /* prefetch E2 value for t+1 (id fetched one step earlier) */             \
    HXP = E2[((IDU) << 9) + col];                                             \
    /* prefetch token id for t+2 */                                           \
    IDL = x[(row << 10) + ((t_ + 2 > SEQ - 1) ? SEQ - 1 : t_ + 2)];           \
    /* h_prev @ W_h : int8 MFMA (A rows replicated from the single h row) */  \
    i32x4 acc[2] = {};                                                        \
    _Pragma("unroll") for (int kt = 0; kt < 8; ++kt) {                        \
      i32x4 a = *(const i32x4*)(&hbuf[PH][(kt << 6) + (lhi << 4)]);           \
      _Pragma("unroll") for (int nt = 0; nt < 2; ++nt)                        \
        acc[nt] = __builtin_amdgcn_mfma_i32_16x16x64_i8(a, bfr[nt][kt],       \
                                                        acc[nt], 0, 0, 0);    \
    }                                                                         \
    /* nontemporal history store (keeps E2 resident in L2) */                 \
    if (t_ > 0 && tid < 32)                                                   \
      __builtin_nontemporal_store(fv, (i32x4*)(hist +                         \
          (((size_t)(row << 10) + (t_ - 1)) << 10) + (tid << 4)));            \
    /* select this lane's nt = lhi&1 copy (all copies valid) */               \
    int av = (lhi & 1) ? acc[1][0] : acc[0][0];                               \
    /* z = acc*inv + hx ; h = tanh(z) ; emit int8 */                          \
    float z = fmaf((float)av, inv, HXU);                                      \
    float e = __builtin_amdgcn_exp2f(z * TC);                                 \
    float h = fmaf(-2.f, __builtin_amdgcn_rcpf(1.f + e), 1.f);                \
    hbuf[1 - (PH)][col] = (char)__float2int_rn(h * 127.f);                    \
    if (t_ == SEQ - 1) fh[(row << 9) + col] = h;                              \
    asm volatile("s_waitcnt lgkmcnt(0)" ::: "memory");                        \
    __builtin_amdgcn_sched_barrier(0);                                        \
    __builtin_amdgcn_s_barrier();                                             \
    __builtin_amdgcn_sched_barrier(0);                                        \
  }

  for (int T2 = 0; T2 < SEQ / 2; ++T2) {
    STEP(2 * T2,     0, hxA, hxB, idA, idB)
    STEP(2 * T2 + 1, 1, hxB, hxA, idB, idA)
  }
#undef STEP

  // final flush: outputs[1023] lives in hbuf[0] (written by step 1023)
  if (tid < 32) {
    i32x4 fv = *(const i32x4*)(&hbuf[0][tid << 4]);
    __builtin_nontemporal_store(fv, (i32x4*)(hist +
        (((size_t)(row << 10) + (SEQ - 1)) << 10) + (tid << 4)));
  }
}

// ---------------------------------------------------------------------------
// Logits: A = int8 hist (512B prefix of each 1024B row slot) dequantized to
// bf16 during LDS staging (exact: |q|<=127 ints are exact bf16; 1/127 folded
// into WoT). GEMM in-place over d_out as before.
// ---------------------------------------------------------------------------
__global__ __launch_bounds__(256) void k_logits(const char* __restrict__ hist,
                                                const unsigned short* __restrict__ WoT,
                                                const float* __restrict__ bo, float* out)
{
  __shared__ __align__(16) char As[64 * 1024];
  const int tid = threadIdx.x;
  const int m0 = blockIdx.x * 64;

  // stage + dequant: 64 rows x 512 int8 -> bf16 tile with 16B-granule swizzle
  for (int i = tid; i < 1024; i += 256) {
    const int row = i >> 4, seg = i & 15;                 // 32 int8 cols/seg
    const char* src = hist + (size_t)(m0 + row) * 1024 + seg * 32;
    i32x4 w0 = *(const i32x4*)(src);
    i32x4 w1 = *(const i32x4*)(src + 16);
    unsigned od[16];
    #pragma unroll
    for (int d = 0; d < 8; ++d) {
      const unsigned dw = (unsigned)(d < 4 ? w0[d] : w1[d - 4]);
      const int q0 = (int)(signed char)(dw & 0xffu);
      const int q1 = (int)(signed char)((dw >> 8) & 0xffu);
      const int q2 = (int)(signed char)((dw >> 16) & 0xffu);
      const int q3 = (int)(signed char)(dw >> 24);
      const unsigned u0 = __builtin_bit_cast(unsigned, (float)q0);
      const unsigned u1 = __builtin_bit_cast(unsigned, (float)q1);
      const unsigned u2 = __builtin_bit_cast(unsigned, (float)q2);
      const unsigned u3 = __builtin_bit_cast(unsigned, (float)q3);
      od[2 * d]     = (u0 >> 16) | (u1 & 0xffff0000u);
      od[2 * d + 1] = (u2 >> 16) | (u3 & 0xffff0000u);
    }
    #pragma unroll
    for (int q = 0; q < 4; ++q) {
      i32x4 v = {(int)od[4 * q], (int)od[4 * q + 1],
                 (int)od[4 * q + 2], (int)od[4 * q + 3]};
      const int off = seg * 64 + q * 16;
      *(i32x4*)(&As[row * 1024 + (off ^ ((row & 7) << 4))]) = v;
    }
  }
  __syncthreads();

  const int wv = tid >> 6, lane = tid & 63, lrow = lane & 15, lhi = lane >> 4;
  const int cb = wv << 6;
  f32x4 acc[4][4] = {};
  #pragma unroll
  for (int kt = 0; kt < 16; ++kt) {
    s16x8 a[4], b[4];
    #pragma unroll
    for (int mt = 0; mt < 4; ++mt) {
      const int row = mt * 16 + lrow;
      a[mt] = *(const s16x8*)(&As[row * 1024 + ((kt * 64 + lhi * 16) ^ ((row & 7) << 4))]);
    }
    #pragma unroll
    for (int nt = 0; nt < 4; ++nt) {
      const int col = cb + nt * 16 + lrow;
      b[nt] = *(const s16x8*)((const char*)WoT + col * 1024 + kt * 64 + lhi * 16);
    }
    #pragma unroll
    for (int mt = 0; mt < 4; ++mt)
      #pragma unroll
      for (int nt = 0; nt < 4; ++nt)
        acc[mt][nt] = __builtin_amdgcn_mfma_f32_16x16x32_bf16(a[mt], b[nt], acc[mt][nt], 0, 0, 0);
  }
  #pragma unroll
  for (int nt = 0; nt < 4; ++nt) {
    const float bb = bo[cb + nt * 16 + lrow];
    #pragma unroll
    for (int mt = 0; mt < 4; ++mt)
      #pragma unroll
      for (int r = 0; r < 4; ++r)
        out[(size_t)(m0 + mt * 16 + lhi * 4 + r) * OUT_D + cb + nt * 16 + lrow] =
            acc[mt][nt][r] + bb;
  }
}

// ---------------------------------------------------------------------------
extern "C" void kernel_launch(void* const* d_in, const int* in_sizes, int n_in,
                              void* d_out, int out_size, void* d_ws, size_t ws_size,
                              hipStream_t stream)
{
  const int*   x   = (const int*)  d_in[0];
  const float* h0  = (const float*)d_in[1];
  const float* emb = (const float*)d_in[2];
  const float* We  = (const float*)d_in[3];
  const float* Wh  = (const float*)d_in[4];
  const float* bh  = (const float*)d_in[5];
  const float* Wo  = (const float*)d_in[6];
  const float* bo  = (const float*)d_in[7];
  float* out = (float*)d_out;
  char*  ws  = (char*)d_ws;

  float*          E2  = (float*)ws;                              // 512 KB
  i32x4*          WhF = (i32x4*)(ws + (512 << 10));              // 256 KB
  unsigned short* WoT = (unsigned short*)(ws + (768 << 10));     // 256 KB

  k_e2    <<<VOCAB, HID,   0, stream>>>(emb, We, bh, E2);
  k_whfrag<<<64,    256,   0, stream>>>(Wh, WhF);
  k_wot   <<<HID,   OUT_D, 0, stream>>>(Wo, WoT);

  // int8 h history lives in the 512B prefix of each logits row of d_out;
  // k_logits then overwrites each row in-place after staging it to LDS.
  k_scan  <<<BATCH, 1024, 0, stream>>>(x, h0, E2, WhF,
                                       (char*)d_out,
                                       out + (size_t)BATCH * SEQ * OUT_D);
  k_logits<<<(BATCH * SEQ) / 64, 256, 0, stream>>>(
      (const char*)d_out, WoT, bo, out);
}